// Round 1
// 682.574 us; speedup vs baseline: 1.0069x; 1.0069x over previous
//
#include <hip/hip_runtime.h>
#include <stdint.h>
#include <stddef.h>

#define TDIM 4096
#define DDIM 1024
#define HDIM 64
#define BDIM 8
#define MROWS (BDIM * TDIM)   // 32768
#define KCAT (DDIM + HDIM)    // 1088
#define DD (DDIM * DDIM)
#define HD (HDIM * DDIM)

typedef unsigned short ushort_t;
typedef __attribute__((ext_vector_type(8))) short short8;
typedef __attribute__((ext_vector_type(4))) float floatx4;

__device__ __forceinline__ unsigned short f2bf(float f) {
  unsigned u = __float_as_uint(f);
  u += 0x7fffu + ((u >> 16) & 1u);          // round-to-nearest-even
  return (unsigned short)(u >> 16);
}
__device__ __forceinline__ float bf2f(unsigned short s) {
  return __uint_as_float(((unsigned)s) << 16);
}
__device__ __forceinline__ float softplusf(float x) {
  return x > 20.f ? x : log1pf(expf(x));
}

// ---------------- fused weight prep (one launch) ----------------
__global__ void k_prep(const float* __restrict__ W1, const float* __restrict__ W2,
                       const float* __restrict__ Wlast, const float* __restrict__ dwm,
                       const float* __restrict__ Bw, const float* __restrict__ Dw,
                       const float* __restrict__ Cw, const float* __restrict__ Cb,
                       const float* __restrict__ Db,
                       ushort_t* __restrict__ wcat, ushort_t* __restrict__ wlb,
                       ushort_t* __restrict__ dwbw, ushort_t* __restrict__ bcat,
                       float* __restrict__ biasCD) {
  int i = blockIdx.x * 256 + threadIdx.x;
  if (i < DD) { wcat[i] = f2bf(W1[i]); return; }
  i -= DD;
  if (i < DD) { wcat[DD + i] = f2bf(W2[i]); return; }
  i -= DD;
  if (i < DD) { wlb[i] = f2bf(Wlast[i]); return; }
  i -= DD;
  if (i < HD) { dwbw[i] = f2bf(dwm[i]); return; }
  i -= HD;
  if (i < HD) { dwbw[HD + i] = f2bf(Bw[i]); return; }
  i -= HD;
  if (i < DDIM * KCAT) {
    const int row = i / KCAT, k = i - row * KCAT;
    const float v = (k < DDIM) ? Dw[row * DDIM + k] : Cw[row * HDIM + (k - DDIM)];
    bcat[i] = f2bf(v);
    return;
  }
  i -= DDIM * KCAT;
  if (i < DDIM) biasCD[i] = Cb[i] + Db[i];
}

// ---------------- RMSNorm: x (f32) -> xn (bf16) ----------------
__global__ __launch_bounds__(256) void k_rms(const float* __restrict__ x,
                                             const float* __restrict__ nw,
                                             ushort_t* __restrict__ xn) {
  const int row = blockIdx.x;
  const int tid = threadIdx.x;
  const size_t base = (size_t)row * DDIM + tid * 4;
  const float4 xv = *(const float4*)(x + base);
  float ss = xv.x * xv.x + xv.y * xv.y + xv.z * xv.z + xv.w * xv.w;
  for (int off = 32; off > 0; off >>= 1) ss += __shfl_down(ss, off, 64);
  __shared__ float sws[4];
  const int lane = tid & 63, w = tid >> 6;
  if (lane == 0) sws[w] = ss;
  __syncthreads();
  const float tot = sws[0] + sws[1] + sws[2] + sws[3];
  const float scale = rsqrtf(tot * (1.0f / DDIM) + 1.1920929e-7f);
  const float4 nwv = *(const float4*)(nw + tid * 4);
  ushort4 o;
  o.x = f2bf(xv.x * scale * nwv.x);
  o.y = f2bf(xv.y * scale * nwv.y);
  o.z = f2bf(xv.z * scale * nwv.z);
  o.w = f2bf(xv.w * scale * nwv.w);
  *(ushort4*)(xn + base) = o;
}

// ---------------- causal depthwise conv k=3 + silu (vectorized x8) ----------------
__global__ __launch_bounds__(256) void k_conv(const ushort_t* __restrict__ xz,
                                              const float* __restrict__ cw,
                                              const float* __restrict__ cb,
                                              ushort_t* __restrict__ acat) {
  const size_t eidx = ((size_t)blockIdx.x * 256 + threadIdx.x) * 8;  // over MROWS*DDIM
  const int d = (int)(eidx & (DDIM - 1));
  const size_t m = eidx >> 10;
  const int t = (int)(m & (TDIM - 1));
  const size_t s = m * 2048 + d;
  const short8 r2 = *(const short8*)(xz + s);
  short8 r1 = {0,0,0,0,0,0,0,0}, r0 = {0,0,0,0,0,0,0,0};
  if (t >= 1) r1 = *(const short8*)(xz + s - 2048);
  if (t >= 2) r0 = *(const short8*)(xz + s - 4096);
  short8 o;
#pragma unroll
  for (int e = 0; e < 8; ++e) {
    const int de = d + e;
    float v = bf2f((ushort_t)r2[e]) * cw[de * 3 + 2]
            + bf2f((ushort_t)r1[e]) * cw[de * 3 + 1]
            + bf2f((ushort_t)r0[e]) * cw[de * 3 + 0]
            + cb[de];
    o[e] = (short)f2bf(v / (1.f + __expf(-v)));
  }
  *(short8*)(acat + m * KCAT + d) = o;
}

// ---------------- fused delta + selective scan: one block per (b,h) channel ----------------
__global__ __launch_bounds__(256) void k_scan(const float* __restrict__ preG,
                                              const float* __restrict__ db,
                                              const float* __restrict__ Bb,
                                              const float* __restrict__ A,
                                              ushort_t* __restrict__ hT) {
  const int ch = blockIdx.x;           // 0..511
  const int b = ch >> 6, h = ch & 63;
  const int tid = threadIdx.x;
  const float dbh = db[h], Bbh = Bb[h];
  const float al = -softplusf(A[h]);
  const size_t base1 = (size_t)h * MROWS + (size_t)b * TDIM + (size_t)tid * 16;
  const size_t base2 = base1 + (size_t)64 * MROWS;

  float a[16], bbv[16];
#pragma unroll
  for (int k4 = 0; k4 < 4; ++k4) {
    const float4 p1 = *(const float4*)(preG + base1 + k4 * 4);
    const float4 p2 = *(const float4*)(preG + base2 + k4 * 4);
    const float pp1[4] = {p1.x, p1.y, p1.z, p1.w};
    const float pp2[4] = {p2.x, p2.y, p2.z, p2.w};
#pragma unroll
    for (int e = 0; e < 4; ++e) {
      const float delta = softplusf(pp1[e] + dbh);
      a[k4 * 4 + e] = delta * al;
      bbv[k4 * 4 + e] = delta * (pp2[e] + Bbh);
    }
  }
  float run = 0.f;
#pragma unroll
  for (int k = 0; k < 16; ++k) { run += a[k]; a[k] = run; }  // local inclusive

  __shared__ float sh[256];
  sh[tid] = run;
  __syncthreads();
  for (int s = 1; s < 256; s <<= 1) {
    float v = (tid >= s) ? sh[tid - s] : 0.f;
    __syncthreads();
    sh[tid] += v;
    __syncthreads();
  }
  const float off = (tid > 0) ? sh[tid - 1] : 0.f;
  __syncthreads();

  float term[16];
  float prev = off;  // exclusive prefix (unclipped)
#pragma unroll
  for (int k = 0; k < 16; ++k) {
    const float Pk = off + a[k];
    const float Ashift = fminf(fmaxf(prev, -20.f), 20.f);
    term[k] = bbv[k] * expf(-Ashift);
    a[k] = fminf(fmaxf(Pk, -20.f), 20.f);  // clipped A_cum
    prev = Pk;
  }

  float run2 = 0.f;
#pragma unroll
  for (int k = 0; k < 16; ++k) { run2 += term[k]; term[k] = run2; }
  sh[tid] = run2;
  __syncthreads();
  for (int s = 1; s < 256; s <<= 1) {
    float v = (tid >= s) ? sh[tid - s] : 0.f;
    __syncthreads();
    sh[tid] += v;
    __syncthreads();
  }
  const float off2 = (tid > 0) ? sh[tid - 1] : 0.f;

  ushort_t* dst = hT + (size_t)h * MROWS + (size_t)b * TDIM + (size_t)tid * 16;
#pragma unroll
  for (int k = 0; k < 16; ++k) {
    dst[k] = f2bf(expf(a[k]) * (off2 + term[k]));
  }
}

// ---------------- transpose hT[64][M] -> acat[:, 1024:1088] ----------------
__global__ __launch_bounds__(256) void k_htrans(const ushort_t* __restrict__ hT,
                                                ushort_t* __restrict__ acat) {
  __shared__ ushort_t t[64 * 256];
  const int tid = threadIdx.x;
  const int m0 = blockIdx.x * 256;
#pragma unroll
  for (int p = 0; p < 8; ++p) {
    const int e = p * 2048 + tid * 8;
    const int h = e >> 8, mm = e & 255;
    *(short8*)(t + e) = *(const short8*)(hT + (size_t)h * MROWS + m0 + mm);
  }
  __syncthreads();
  ushort_t* dst = acat + (size_t)(m0 + tid) * KCAT + DDIM;
#pragma unroll
  for (int p = 0; p < 8; ++p) {
    short8 v;
#pragma unroll
    for (int e = 0; e < 8; ++e) v[e] = t[(p * 8 + e) * 256 + tid];
    *(short8*)(dst + p * 8) = v;
  }
}

// ---------------- 128x128 GEMM (kept for the skinny M=128 step 4) ----------------
__device__ __forceinline__ void stage128x64(const ushort_t* __restrict__ G, int row0,
                                            int ld, int kc, ushort_t* s, int wave, int lane) {
  const int rsub = lane >> 3;   // row within 8-row group
  const int cpos = lane & 7;    // dest chunk position
  using gp_t = const unsigned int __attribute__((address_space(1)))*;
  using lp_t = unsigned int __attribute__((address_space(3)))*;
#pragma unroll
  for (int g = 0; g < 4; ++g) {
    const int rg = wave * 4 + g;           // 0..15 row-group
    const int r = rg * 8 + rsub;           // tile row
    const int c = cpos ^ rsub;             // source chunk (r&7 == rsub)
    const ushort_t* src = G + (size_t)(row0 + r) * (size_t)ld + (size_t)(kc + c * 8);
    __builtin_amdgcn_global_load_lds((gp_t)(const void*)src, (lp_t)(void*)(s + rg * 512),
                                     16, 0, 0);
  }
}

__global__ __launch_bounds__(256, 4) void k_gemm(
    const ushort_t* __restrict__ A, int lda,
    const ushort_t* __restrict__ Bt, int ldb,
    int nB, int Kdim, int mode,
    float* __restrict__ outF, ushort_t* __restrict__ outB, int ldc,
    const float* __restrict__ bias,
    const ushort_t* __restrict__ zmat, int ldz,
    const float* __restrict__ resid) {
  __shared__ alignas(16) ushort_t smem[128 * 128];  // 32KB: sA | sB, reused as C-tile
  ushort_t* sA = smem;
  ushort_t* sB = smem + 128 * 64;
  const int tid = threadIdx.x;
  const int wave = tid >> 6, lane = tid & 63;

  const int per = gridDim.x >> 3;
  const int xcd = blockIdx.x & 7, slot = blockIdx.x >> 3;
  const int tile = xcd * per + slot;
  const int m0 = (tile / nB) * 128, n0 = (tile % nB) * 128;

  const int half_m = (wave & 1) * 64, half_n = (wave >> 1) * 64;
  const int quad = lane >> 4, l16 = lane & 15;

  floatx4 acc[4][4];
#pragma unroll
  for (int i = 0; i < 4; ++i)
#pragma unroll
    for (int j = 0; j < 4; ++j) acc[i][j] = floatx4{0.f, 0.f, 0.f, 0.f};

  for (int kc = 0; kc < Kdim; kc += 64) {
    stage128x64(A, m0, lda, kc, sA, wave, lane);
    stage128x64(Bt, n0, ldb, kc, sB, wave, lane);
    __syncthreads();
#pragma unroll
    for (int s = 0; s < 2; ++s) {
      short8 af[4], bfr[4];
#pragma unroll
      for (int i = 0; i < 4; ++i) {
        const int r = half_m + i * 16 + l16;
        const int cp = (s * 4 + quad) ^ (r & 7);
        af[i] = *(const short8*)(sA + r * 64 + cp * 8);
      }
#pragma unroll
      for (int j = 0; j < 4; ++j) {
        const int r = half_n + j * 16 + l16;
        const int cp = (s * 4 + quad) ^ (r & 7);
        bfr[j] = *(const short8*)(sB + r * 64 + cp * 8);
      }
#pragma unroll
      for (int i = 0; i < 4; ++i)
#pragma unroll
        for (int j = 0; j < 4; ++j)
          acc[i][j] = __builtin_amdgcn_mfma_f32_16x16x32_bf16(af[i], bfr[j], acc[i][j], 0, 0, 0);
    }
    __syncthreads();
  }

#pragma unroll
  for (int i = 0; i < 4; ++i)
#pragma unroll
    for (int j = 0; j < 4; ++j)
#pragma unroll
      for (int rg = 0; rg < 4; ++rg) {
        const int r = half_m + i * 16 + quad * 4 + rg;
        const int c = half_n + j * 16 + l16;
        smem[r * 128 + c] = f2bf(acc[i][j][rg]);
      }
  __syncthreads();

#pragma unroll
  for (int p = 0; p < 8; ++p) {
    const int r = p * 16 + (tid >> 4);
    const int c = (tid & 15) * 8;
    short8 v8 = *(const short8*)(smem + r * 128 + c);
    const size_t m = (size_t)(m0 + r);
    const int n = n0 + c;
    if (mode == 0) {
      *(short8*)(outB + m * (size_t)ldc + n) = v8;
    } else if (mode == 1) {
      float* o = outF + m * (size_t)ldc + n;
#pragma unroll
      for (int e = 0; e < 8; ++e) o[e] = bf2f((ushort_t)v8[e]);
    } else if (mode == 2) {
      const short8 z8 = *(const short8*)(zmat + m * (size_t)ldz + n);
      short8 o;
#pragma unroll
      for (int e = 0; e < 8; ++e) {
        const float v = bf2f((ushort_t)v8[e]) + bias[n + e];
        const float zf = bf2f((ushort_t)z8[e]);
        o[e] = (short)f2bf(v * (zf / (1.f + __expf(-zf))));
      }
      *(short8*)(outB + m * (size_t)ldc + n) = o;
    } else {
      const float* rs = resid + m * (size_t)ldc + n;
      float* o = outF + m * (size_t)ldc + n;
#pragma unroll
      for (int e = 0; e < 8; ++e) o[e] = bf2f((ushort_t)v8[e]) + rs[e];
    }
  }
}

// ---------------- 256x256 8-phase GEMM (T1+T2+T3+T4+T5), 512 threads ----------------
// 8 waves (2M x 4N), per-wave 128x64 output (acc[8][4]), BK=64, double-buffered
// 128 KiB LDS. Counted vmcnt(4) at each K-tile boundary (never drains to 0 in
// steady state). Staging units (2 global_load_lds/thread each):
//   KIND 0: A rows {0-63,128-191}   (consumed by end of phase 2 -> safe @p1 next buf)
//   KIND 1: A rows {64-127,192-255} (consumed by end of phase 4 -> safe @p2 next buf)
//   KIND 2: B rows {0-127}          (all B consumed by end of phase 2 -> safe @p3 CUR buf)
//   KIND 3: B rows {128-255}        (safe @p4 CUR buf)
template <int KIND>
__device__ __forceinline__ void stage_unit(const ushort_t* __restrict__ G, int row0, int ld,
                                           int kc, ushort_t* s, int wave, int lane) {
  using gp_t = const unsigned int __attribute__((address_space(1)))*;
  using lp_t = unsigned int __attribute__((address_space(3)))*;
  const int rsub = lane >> 3;
  const int cpos = lane & 7;
#pragma unroll
  for (int g = 0; g < 2; ++g) {
    const int idx = wave * 2 + g;
    int rg;
    if (KIND == 0)      rg = idx + (idx >= 8 ? 8 : 0);
    else if (KIND == 1) rg = idx + 8 + (idx >= 8 ? 8 : 0);
    else if (KIND == 2) rg = idx;
    else                rg = idx + 16;
    const int r = rg * 8 + rsub;
    const int c = cpos ^ rsub;   // XOR-chunk pre-swizzle of the GLOBAL source
    const ushort_t* src = G + (size_t)(row0 + r) * (size_t)ld + (size_t)(kc + c * 8);
    __builtin_amdgcn_global_load_lds((gp_t)(const void*)src, (lp_t)(void*)(s + rg * 512),
                                     16, 0, 0);
  }
}

__device__ __forceinline__ short8 lds_frag(const ushort_t* s, int row, int chunk) {
  return *(const short8*)(s + row * 64 + ((chunk ^ (row & 7)) * 8));
}

__global__ __launch_bounds__(512, 2) void k_gemm256(
    const ushort_t* __restrict__ A, int lda,
    const ushort_t* __restrict__ Bt, int ldb,
    int nB, int Kdim, int mode,
    float* __restrict__ outF, ushort_t* __restrict__ outB, int ldc,
    const float* __restrict__ bias,
    const ushort_t* __restrict__ zmat, int ldz,
    const float* __restrict__ resid) {
  __shared__ alignas(16) ushort_t smem[65536];  // 128 KiB: buf0{A,B} | buf1{A,B}
  const int tid = threadIdx.x;
  const int wave = tid >> 6, lane = tid & 63;
  const int wm = wave >> 2, wn = wave & 3;
  const int quad = lane >> 4, l16 = lane & 15;

  const int per = gridDim.x >> 3;
  const int xcd = blockIdx.x & 7, slot = blockIdx.x >> 3;
  const int tile = xcd * per + slot;
  const int m0 = (tile / nB) * 256, n0 = (tile % nB) * 256;
  const int NT = Kdim >> 6;

  floatx4 acc[8][4];
#pragma unroll
  for (int i = 0; i < 8; ++i)
#pragma unroll
    for (int j = 0; j < 4; ++j) acc[i][j] = floatx4{0.f, 0.f, 0.f, 0.f};

  // prologue: tile0 {B1,B2,A_lo,A_hi} + tile1 {B1,B2}; wait tile0, leave 4 in flight
  stage_unit<2>(Bt, n0, ldb, 0, smem + 16384, wave, lane);
  stage_unit<3>(Bt, n0, ldb, 0, smem + 16384, wave, lane);
  stage_unit<0>(A, m0, lda, 0, smem, wave, lane);
  stage_unit<1>(A, m0, lda, 0, smem, wave, lane);
  if (NT > 1) {
    stage_unit<2>(Bt, n0, ldb, 64, smem + 32768 + 16384, wave, lane);
    stage_unit<3>(Bt, n0, ldb, 64, smem + 32768 + 16384, wave, lane);
    asm volatile("s_waitcnt vmcnt(4)");
  } else {
    asm volatile("s_waitcnt vmcnt(0)");
  }
  __builtin_amdgcn_s_barrier();

  short8 af[2][4], bf[2][2][2];
  const int rowA = wm * 128 + l16;
  const int rowB = wn * 64 + l16;

  for (int t = 0; t < NT; ++t) {
    ushort_t* sAc = smem + (t & 1) * 32768;
    ushort_t* sBc = sAc + 16384;
    ushort_t* sAn = smem + ((t + 1) & 1) * 32768;
    const int kc1 = (t + 1) << 6, kc2 = (t + 2) << 6;
    const bool pA = (t + 1 < NT), pB = (t + 2 < NT);

    // ---- phase 1: Q0 (m 0-3, n 0-1), stage A_lo(t+1) -> next buf
#pragma unroll
    for (int kk = 0; kk < 2; ++kk) {
#pragma unroll
      for (int i = 0; i < 4; ++i) af[kk][i] = lds_frag(sAc, rowA + i * 16, kk * 4 + quad);
#pragma unroll
      for (int j = 0; j < 2; ++j) bf[0][kk][j] = lds_frag(sBc, rowB + j * 16, kk * 4 + quad);
    }
    if (pA) stage_unit<0>(A, m0, lda, kc1, sAn, wave, lane);
    __builtin_amdgcn_s_barrier();
    asm volatile("s_waitcnt lgkmcnt(0)");
    __builtin_amdgcn_s_setprio(1);
#pragma unroll
    for (int kk = 0; kk < 2; ++kk)
#pragma unroll
      for (int i = 0; i < 4; ++i)
#pragma unroll
        for (int j = 0; j < 2; ++j)
          acc[i][j] = __builtin_amdgcn_mfma_f32_16x16x32_bf16(af[kk][i], bf[0][kk][j], acc[i][j], 0, 0, 0);
    __builtin_amdgcn_s_setprio(0);
    __builtin_amdgcn_s_barrier();

    // ---- phase 2: Q1 (m 0-3, n 2-3), stage A_hi(t+1) -> next buf
#pragma unroll
    for (int kk = 0; kk < 2; ++kk)
#pragma unroll
      for (int j = 0; j < 2; ++j) bf[1][kk][j] = lds_frag(sBc, rowB + (2 + j) * 16, kk * 4 + quad);
    if (pA) stage_unit<1>(A, m0, lda, kc1, sAn, wave, lane);
    __builtin_amdgcn_s_barrier();
    asm volatile("s_waitcnt lgkmcnt(0)");
    __builtin_amdgcn_s_setprio(1);
#pragma unroll
    for (int kk = 0; kk < 2; ++kk)
#pragma unroll
      for (int i = 0; i < 4; ++i)
#pragma unroll
        for (int j = 0; j < 2; ++j)
          acc[i][2 + j] = __builtin_amdgcn_mfma_f32_16x16x32_bf16(af[kk][i], bf[1][kk][j], acc[i][2 + j], 0, 0, 0);
    __builtin_amdgcn_s_setprio(0);
    __builtin_amdgcn_s_barrier();

    // ---- phase 3: Q2 (m 4-7, n 0-1), stage B1(t+2) -> CURRENT buf (B consumed @p2)
#pragma unroll
    for (int kk = 0; kk < 2; ++kk)
#pragma unroll
      for (int i = 0; i < 4; ++i) af[kk][i] = lds_frag(sAc, rowA + 64 + i * 16, kk * 4 + quad);
    if (pB) stage_unit<2>(Bt, n0, ldb, kc2, sBc, wave, lane);
    __builtin_amdgcn_s_barrier();
    asm volatile("s_waitcnt lgkmcnt(0)");
    __builtin_amdgcn_s_setprio(1);
#pragma unroll
    for (int kk = 0; kk < 2; ++kk)
#pragma unroll
      for (int i = 0; i < 4; ++i)
#pragma unroll
        for (int j = 0; j < 2; ++j)
          acc[4 + i][j] = __builtin_amdgcn_mfma_f32_16x16x32_bf16(af[kk][i], bf[0][kk][j], acc[4 + i][j], 0, 0, 0);
    __builtin_amdgcn_s_setprio(0);
    __builtin_amdgcn_s_barrier();

    // ---- phase 4: Q3 (m 4-7, n 2-3), stage B2(t+2) -> CURRENT buf; tile-boundary vmcnt
    if (pB) stage_unit<3>(Bt, n0, ldb, kc2, sBc, wave, lane);
    __builtin_amdgcn_s_barrier();
    __builtin_amdgcn_s_setprio(1);
#pragma unroll
    for (int kk = 0; kk < 2; ++kk)
#pragma unroll
      for (int i = 0; i < 4; ++i)
#pragma unroll
        for (int j = 0; j < 2; ++j)
          acc[4 + i][2 + j] = __builtin_amdgcn_mfma_f32_16x16x32_bf16(af[kk][i], bf[1][kk][j], acc[4 + i][2 + j], 0, 0, 0);
    __builtin_amdgcn_s_setprio(0);
    if (pB) asm volatile("s_waitcnt vmcnt(4)");   // tile t+1 landed; B(t+2) in flight
    else    asm volatile("s_waitcnt vmcnt(0)");   // pipeline drain (last 2 tiles)
    __builtin_amdgcn_s_barrier();
  }

  // Epilogue through LDS: acc (col=lane&15, row=quad*4+reg) -> bf16 [256][256]
#pragma unroll
  for (int i = 0; i < 8; ++i)
#pragma unroll
    for (int j = 0; j < 4; ++j)
#pragma unroll
      for (int rg = 0; rg < 4; ++rg) {
        const int r = wm * 128 + i * 16 + quad * 4 + rg;
        const int c = wn * 64 + j * 16 + l16;
        smem[r * 256 + c] = f2bf(acc[i][j][rg]);
      }
  __syncthreads();

#pragma unroll
  for (int p = 0; p < 16; ++p) {
    const int r = p * 16 + (tid >> 5);
    const int c = (tid & 31) * 8;
    short8 v8 = *(const short8*)(smem + r * 256 + c);
    const size_t m = (size_t)(m0 + r);
    const int n = n0 + c;
    if (mode == 0) {
      *(short8*)(outB + m * (size_t)ldc + n) = v8;
    } else if (mode == 1) {
      float* o = outF + m * (size_t)ldc + n;
#pragma unroll
      for (int e = 0; e < 8; ++e) o[e] = bf2f((ushort_t)v8[e]);
    } else if (mode == 2) {
      const short8 z8 = *(const short8*)(zmat + m * (size_t)ldz + n);
      short8 o;
#pragma unroll
      for (int e = 0; e < 8; ++e) {
        const float v = bf2f((ushort_t)v8[e]) + bias[n + e];
        const float zf = bf2f((ushort_t)z8[e]);
        o[e] = (short)f2bf(v * (zf / (1.f + __expf(-zf))));
      }
      *(short8*)(outB + m * (size_t)ldc + n) = o;
    } else {
      const float* rs = resid + m * (size_t)ldc + n;
      float* o = outF + m * (size_t)ldc + n;
#pragma unroll
      for (int e = 0; e < 8; ++e) o[e] = bf2f((ushort_t)v8[e]) + rs[e];
    }
  }
}

// ---------------- host ----------------
extern "C" void kernel_launch(void* const* d_in, const int* in_sizes, int n_in,
                              void* d_out, int out_size, void* d_ws, size_t ws_size,
                              hipStream_t stream) {
  const float* x      = (const float*)d_in[0];
  const float* norm_w = (const float*)d_in[1];
  const float* W1     = (const float*)d_in[2];
  const float* W2     = (const float*)d_in[3];
  const float* Wlast  = (const float*)d_in[4];
  const float* conv_w = (const float*)d_in[5];
  const float* conv_b = (const float*)d_in[6];
  const float* Aarr   = (const float*)d_in[7];
  const float* Bw     = (const float*)d_in[8];
  const float* Bb     = (const float*)d_in[9];
  const float* Cw     = (const float*)d_in[10];
  const float* Cb     = (const float*)d_in[11];
  const float* Dw     = (const float*)d_in[12];
  const float* Db     = (const float*)d_in[13];
  const float* dwm    = (const float*)d_in[14];
  const float* dbv    = (const float*)d_in[15];

  char* ws = (char*)d_ws;
  ushort_t* xz   = (ushort_t*)(ws + 0);           // M x 2048 bf16 (x_b | z), 128 MB
  ushort_t* acat = (ushort_t*)(ws + 134217728);   // M x 1088 bf16 (xc | h), ~68 MB
  float*   preG  = (float*)(ws + 205520896);      // 128 x M f32 (transposed), 16 MB
  ushort_t* hT   = (ushort_t*)(ws + 222298112);   // 64 x M bf16, 4 MB
  ushort_t* xnu  = (ushort_t*)(ws + 226492416);   // M x 1024 bf16: xn, later u. 64 MB
  ushort_t* wcat = (ushort_t*)(ws + 293601280);   // 2048 x 1024 bf16 (W1; W2), 4 MB
  ushort_t* wlb  = (ushort_t*)(ws + 297795584);   // 1024 x 1024 bf16, 2 MB
  ushort_t* dwbw = (ushort_t*)(ws + 299892736);   // 128 x 1024 bf16 (dw; Bw), 256 KB
  ushort_t* bcat = (ushort_t*)(ws + 300154880);   // 1024 x 1088 bf16 (Dw | Cw), ~2.2 MB
  float*  biasCD = (float*)(ws + 302383104);      // 1024 f32
  float*   outF  = (float*)d_out;

  // 0. fused weight prep (one launch)
  {
    const int total = 3 * DD + 2 * HD + DDIM * KCAT + DDIM;
    k_prep<<<(total + 255) / 256, 256, 0, stream>>>(W1, W2, Wlast, dwm, Bw, Dw, Cw, Cb, Db,
                                                    wcat, wlb, dwbw, bcat, biasCD);
  }

  // 1. RMSNorm -> xn
  k_rms<<<MROWS, 256, 0, stream>>>(x, norm_w, xnu);

  // 2. [x_b | z] = xn @ [W1;W2].T  (fused, N=2048) — 256x256 8-phase
  k_gemm256<<<(MROWS / 256) * 8, 512, 0, stream>>>(xnu, DDIM, wcat, DDIM, 8, DDIM, 0,
                                                   nullptr, xz, 2048, nullptr, nullptr, 0, nullptr);

  // 3. conv + silu -> acat cols [0,1024)
  k_conv<<<(MROWS * DDIM) / (256 * 8), 256, 0, stream>>>(xz, conv_w, conv_b, acat);

  // 4. preG_T = [dw;Bw] @ xc.T  (M=128 output — stays on 128x128 kernel)
  k_gemm<<<256, 256, 0, stream>>>(dwbw, DDIM, acat, KCAT, 256, DDIM, 1,
                                  preG, nullptr, MROWS, nullptr, nullptr, 0, nullptr);

  // 5+6. fused delta + selective scan -> hT (transposed)
  k_scan<<<BDIM * HDIM, 256, 0, stream>>>(preG, dbv, Bb, Aarr, hT);

  // 6b. transpose hT into acat cols [1024,1088)
  k_htrans<<<MROWS / 256, 256, 0, stream>>>(hT, acat);

  // 7. u = (h@Cw.T + xc@Dw.T + Cb + Db) * silu(z)   (K=1088 concat GEMM)
  k_gemm256<<<(MROWS / 256) * 4, 512, 0, stream>>>(acat, KCAT, bcat, KCAT, 4, KCAT, 2,
                                                   nullptr, xnu, DDIM, biasCD, xz + DDIM, 2048, nullptr);

  // 8. out = u @ Wlast.T + x
  k_gemm256<<<(MROWS / 256) * 4, 512, 0, stream>>>(xnu, DDIM, wlb, DDIM, 4, DDIM, 3,
                                                   outF, nullptr, DDIM, nullptr, nullptr, 0, x);

  (void)in_sizes; (void)n_in; (void)out_size; (void)ws_size;
}

// Round 2
// 677.134 us; speedup vs baseline: 1.0150x; 1.0080x over previous
//
#include <hip/hip_runtime.h>
#include <stdint.h>
#include <stddef.h>

#define TDIM 4096
#define DDIM 1024
#define HDIM 64
#define BDIM 8
#define MROWS (BDIM * TDIM)   // 32768
#define KCAT (DDIM + HDIM)    // 1088
#define DD (DDIM * DDIM)
#define HD (HDIM * DDIM)

typedef unsigned short ushort_t;
typedef __attribute__((ext_vector_type(8))) short short8;
typedef __attribute__((ext_vector_type(4))) float floatx4;

__device__ __forceinline__ unsigned short f2bf(float f) {
  unsigned u = __float_as_uint(f);
  u += 0x7fffu + ((u >> 16) & 1u);          // round-to-nearest-even
  return (unsigned short)(u >> 16);
}
__device__ __forceinline__ float bf2f(unsigned short s) {
  return __uint_as_float(((unsigned)s) << 16);
}
__device__ __forceinline__ float softplusf(float x) {
  return x > 20.f ? x : log1pf(expf(x));
}

// ---------------- fused weight prep (one launch) ----------------
__global__ void k_prep(const float* __restrict__ W1, const float* __restrict__ W2,
                       const float* __restrict__ Wlast, const float* __restrict__ dwm,
                       const float* __restrict__ Bw, const float* __restrict__ Dw,
                       const float* __restrict__ Cw, const float* __restrict__ Cb,
                       const float* __restrict__ Db,
                       ushort_t* __restrict__ wcat, ushort_t* __restrict__ wlb,
                       ushort_t* __restrict__ dwbw, ushort_t* __restrict__ bcat,
                       float* __restrict__ biasCD) {
  int i = blockIdx.x * 256 + threadIdx.x;
  if (i < DD) { wcat[i] = f2bf(W1[i]); return; }
  i -= DD;
  if (i < DD) { wcat[DD + i] = f2bf(W2[i]); return; }
  i -= DD;
  if (i < DD) { wlb[i] = f2bf(Wlast[i]); return; }
  i -= DD;
  if (i < HD) { dwbw[i] = f2bf(dwm[i]); return; }
  i -= HD;
  if (i < HD) { dwbw[HD + i] = f2bf(Bw[i]); return; }
  i -= HD;
  if (i < DDIM * KCAT) {
    const int row = i / KCAT, k = i - row * KCAT;
    const float v = (k < DDIM) ? Dw[row * DDIM + k] : Cw[row * HDIM + (k - DDIM)];
    bcat[i] = f2bf(v);
    return;
  }
  i -= DDIM * KCAT;
  if (i < DDIM) biasCD[i] = Cb[i] + Db[i];
}

// ---------------- RMSNorm: x (f32) -> xn (bf16) ----------------
__global__ __launch_bounds__(256) void k_rms(const float* __restrict__ x,
                                             const float* __restrict__ nw,
                                             ushort_t* __restrict__ xn) {
  const int row = blockIdx.x;
  const int tid = threadIdx.x;
  const size_t base = (size_t)row * DDIM + tid * 4;
  const float4 xv = *(const float4*)(x + base);
  float ss = xv.x * xv.x + xv.y * xv.y + xv.z * xv.z + xv.w * xv.w;
  for (int off = 32; off > 0; off >>= 1) ss += __shfl_down(ss, off, 64);
  __shared__ float sws[4];
  const int lane = tid & 63, w = tid >> 6;
  if (lane == 0) sws[w] = ss;
  __syncthreads();
  const float tot = sws[0] + sws[1] + sws[2] + sws[3];
  const float scale = rsqrtf(tot * (1.0f / DDIM) + 1.1920929e-7f);
  const float4 nwv = *(const float4*)(nw + tid * 4);
  ushort4 o;
  o.x = f2bf(xv.x * scale * nwv.x);
  o.y = f2bf(xv.y * scale * nwv.y);
  o.z = f2bf(xv.z * scale * nwv.z);
  o.w = f2bf(xv.w * scale * nwv.w);
  *(ushort4*)(xn + base) = o;
}

// ---------------- causal depthwise conv k=3 + silu (vectorized x8) ----------------
__global__ __launch_bounds__(256) void k_conv(const ushort_t* __restrict__ xz,
                                              const float* __restrict__ cw,
                                              const float* __restrict__ cb,
                                              ushort_t* __restrict__ acat) {
  const size_t eidx = ((size_t)blockIdx.x * 256 + threadIdx.x) * 8;  // over MROWS*DDIM
  const int d = (int)(eidx & (DDIM - 1));
  const size_t m = eidx >> 10;
  const int t = (int)(m & (TDIM - 1));
  const size_t s = m * 2048 + d;
  const short8 r2 = *(const short8*)(xz + s);
  short8 r1 = {0,0,0,0,0,0,0,0}, r0 = {0,0,0,0,0,0,0,0};
  if (t >= 1) r1 = *(const short8*)(xz + s - 2048);
  if (t >= 2) r0 = *(const short8*)(xz + s - 4096);
  short8 o;
#pragma unroll
  for (int e = 0; e < 8; ++e) {
    const int de = d + e;
    float v = bf2f((ushort_t)r2[e]) * cw[de * 3 + 2]
            + bf2f((ushort_t)r1[e]) * cw[de * 3 + 1]
            + bf2f((ushort_t)r0[e]) * cw[de * 3 + 0]
            + cb[de];
    o[e] = (short)f2bf(v / (1.f + __expf(-v)));
  }
  *(short8*)(acat + m * KCAT + d) = o;
}

// ---------------- fused delta + selective scan: one block per (b,h) channel ----------------
__global__ __launch_bounds__(256) void k_scan(const float* __restrict__ preG,
                                              const float* __restrict__ db,
                                              const float* __restrict__ Bb,
                                              const float* __restrict__ A,
                                              ushort_t* __restrict__ hT) {
  const int ch = blockIdx.x;           // 0..511
  const int b = ch >> 6, h = ch & 63;
  const int tid = threadIdx.x;
  const float dbh = db[h], Bbh = Bb[h];
  const float al = -softplusf(A[h]);
  const size_t base1 = (size_t)h * MROWS + (size_t)b * TDIM + (size_t)tid * 16;
  const size_t base2 = base1 + (size_t)64 * MROWS;

  float a[16], bbv[16];
#pragma unroll
  for (int k4 = 0; k4 < 4; ++k4) {
    const float4 p1 = *(const float4*)(preG + base1 + k4 * 4);
    const float4 p2 = *(const float4*)(preG + base2 + k4 * 4);
    const float pp1[4] = {p1.x, p1.y, p1.z, p1.w};
    const float pp2[4] = {p2.x, p2.y, p2.z, p2.w};
#pragma unroll
    for (int e = 0; e < 4; ++e) {
      const float delta = softplusf(pp1[e] + dbh);
      a[k4 * 4 + e] = delta * al;
      bbv[k4 * 4 + e] = delta * (pp2[e] + Bbh);
    }
  }
  float run = 0.f;
#pragma unroll
  for (int k = 0; k < 16; ++k) { run += a[k]; a[k] = run; }  // local inclusive

  __shared__ float sh[256];
  sh[tid] = run;
  __syncthreads();
  for (int s = 1; s < 256; s <<= 1) {
    float v = (tid >= s) ? sh[tid - s] : 0.f;
    __syncthreads();
    sh[tid] += v;
    __syncthreads();
  }
  const float off = (tid > 0) ? sh[tid - 1] : 0.f;
  __syncthreads();

  float term[16];
  float prev = off;  // exclusive prefix (unclipped)
#pragma unroll
  for (int k = 0; k < 16; ++k) {
    const float Pk = off + a[k];
    const float Ashift = fminf(fmaxf(prev, -20.f), 20.f);
    term[k] = bbv[k] * expf(-Ashift);
    a[k] = fminf(fmaxf(Pk, -20.f), 20.f);  // clipped A_cum
    prev = Pk;
  }

  float run2 = 0.f;
#pragma unroll
  for (int k = 0; k < 16; ++k) { run2 += term[k]; term[k] = run2; }
  sh[tid] = run2;
  __syncthreads();
  for (int s = 1; s < 256; s <<= 1) {
    float v = (tid >= s) ? sh[tid - s] : 0.f;
    __syncthreads();
    sh[tid] += v;
    __syncthreads();
  }
  const float off2 = (tid > 0) ? sh[tid - 1] : 0.f;

  ushort_t* dst = hT + (size_t)h * MROWS + (size_t)b * TDIM + (size_t)tid * 16;
#pragma unroll
  for (int k = 0; k < 16; ++k) {
    dst[k] = f2bf(expf(a[k]) * (off2 + term[k]));
  }
}

// ---------------- transpose hT[64][M] -> acat[:, 1024:1088] ----------------
__global__ __launch_bounds__(256) void k_htrans(const ushort_t* __restrict__ hT,
                                                ushort_t* __restrict__ acat) {
  __shared__ ushort_t t[64 * 256];
  const int tid = threadIdx.x;
  const int m0 = blockIdx.x * 256;
#pragma unroll
  for (int p = 0; p < 8; ++p) {
    const int e = p * 2048 + tid * 8;
    const int h = e >> 8, mm = e & 255;
    *(short8*)(t + e) = *(const short8*)(hT + (size_t)h * MROWS + m0 + mm);
  }
  __syncthreads();
  ushort_t* dst = acat + (size_t)(m0 + tid) * KCAT + DDIM;
#pragma unroll
  for (int p = 0; p < 8; ++p) {
    short8 v;
#pragma unroll
    for (int e = 0; e < 8; ++e) v[e] = t[(p * 8 + e) * 256 + tid];
    *(short8*)(dst + p * 8) = v;
  }
}

// ---------------- 128x128 GEMM (proven 2-phase; steps 4, 7, 8) ----------------
__device__ __forceinline__ void stage128x64(const ushort_t* __restrict__ G, int row0,
                                            int ld, int kc, ushort_t* s, int wave, int lane) {
  const int rsub = lane >> 3;   // row within 8-row group
  const int cpos = lane & 7;    // dest chunk position
  using gp_t = const unsigned int __attribute__((address_space(1)))*;
  using lp_t = unsigned int __attribute__((address_space(3)))*;
#pragma unroll
  for (int g = 0; g < 4; ++g) {
    const int rg = wave * 4 + g;           // 0..15 row-group
    const int r = rg * 8 + rsub;           // tile row
    const int c = cpos ^ rsub;             // source chunk (r&7 == rsub)
    const ushort_t* src = G + (size_t)(row0 + r) * (size_t)ld + (size_t)(kc + c * 8);
    __builtin_amdgcn_global_load_lds((gp_t)(const void*)src, (lp_t)(void*)(s + rg * 512),
                                     16, 0, 0);
  }
}

__global__ __launch_bounds__(256, 4) void k_gemm(
    const ushort_t* __restrict__ A, int lda,
    const ushort_t* __restrict__ Bt, int ldb,
    int nB, int Kdim, int mode,
    float* __restrict__ outF, ushort_t* __restrict__ outB, int ldc,
    const float* __restrict__ bias,
    const ushort_t* __restrict__ zmat, int ldz,
    const float* __restrict__ resid) {
  __shared__ alignas(16) ushort_t smem[128 * 128];  // 32KB: sA | sB, reused as C-tile
  ushort_t* sA = smem;
  ushort_t* sB = smem + 128 * 64;
  const int tid = threadIdx.x;
  const int wave = tid >> 6, lane = tid & 63;

  const int per = gridDim.x >> 3;
  const int xcd = blockIdx.x & 7, slot = blockIdx.x >> 3;
  const int tile = xcd * per + slot;
  const int m0 = (tile / nB) * 128, n0 = (tile % nB) * 128;

  const int half_m = (wave & 1) * 64, half_n = (wave >> 1) * 64;
  const int quad = lane >> 4, l16 = lane & 15;

  floatx4 acc[4][4];
#pragma unroll
  for (int i = 0; i < 4; ++i)
#pragma unroll
    for (int j = 0; j < 4; ++j) acc[i][j] = floatx4{0.f, 0.f, 0.f, 0.f};

  for (int kc = 0; kc < Kdim; kc += 64) {
    stage128x64(A, m0, lda, kc, sA, wave, lane);
    stage128x64(Bt, n0, ldb, kc, sB, wave, lane);
    __syncthreads();
#pragma unroll
    for (int s = 0; s < 2; ++s) {
      short8 af[4], bfr[4];
#pragma unroll
      for (int i = 0; i < 4; ++i) {
        const int r = half_m + i * 16 + l16;
        const int cp = (s * 4 + quad) ^ (r & 7);
        af[i] = *(const short8*)(sA + r * 64 + cp * 8);
      }
#pragma unroll
      for (int j = 0; j < 4; ++j) {
        const int r = half_n + j * 16 + l16;
        const int cp = (s * 4 + quad) ^ (r & 7);
        bfr[j] = *(const short8*)(sB + r * 64 + cp * 8);
      }
#pragma unroll
      for (int i = 0; i < 4; ++i)
#pragma unroll
        for (int j = 0; j < 4; ++j)
          acc[i][j] = __builtin_amdgcn_mfma_f32_16x16x32_bf16(af[i], bfr[j], acc[i][j], 0, 0, 0);
    }
    __syncthreads();
  }

#pragma unroll
  for (int i = 0; i < 4; ++i)
#pragma unroll
    for (int j = 0; j < 4; ++j)
#pragma unroll
      for (int rg = 0; rg < 4; ++rg) {
        const int r = half_m + i * 16 + quad * 4 + rg;
        const int c = half_n + j * 16 + l16;
        smem[r * 128 + c] = f2bf(acc[i][j][rg]);
      }
  __syncthreads();

#pragma unroll
  for (int p = 0; p < 8; ++p) {
    const int r = p * 16 + (tid >> 4);
    const int c = (tid & 15) * 8;
    short8 v8 = *(const short8*)(smem + r * 128 + c);
    const size_t m = (size_t)(m0 + r);
    const int n = n0 + c;
    if (mode == 0) {
      *(short8*)(outB + m * (size_t)ldc + n) = v8;
    } else if (mode == 1) {
      float* o = outF + m * (size_t)ldc + n;
#pragma unroll
      for (int e = 0; e < 8; ++e) o[e] = bf2f((ushort_t)v8[e]);
    } else if (mode == 2) {
      const short8 z8 = *(const short8*)(zmat + m * (size_t)ldz + n);
      short8 o;
#pragma unroll
      for (int e = 0; e < 8; ++e) {
        const float v = bf2f((ushort_t)v8[e]) + bias[n + e];
        const float zf = bf2f((ushort_t)z8[e]);
        o[e] = (short)f2bf(v * (zf / (1.f + __expf(-zf))));
      }
      *(short8*)(outB + m * (size_t)ldc + n) = o;
    } else {
      const float* rs = resid + m * (size_t)ldc + n;
      float* o = outF + m * (size_t)ldc + n;
#pragma unroll
      for (int e = 0; e < 8; ++e) o[e] = bf2f((ushort_t)v8[e]) + rs[e];
    }
  }
}

// ---------------- 256x256 8-phase GEMM, inline-asm staging (step 2) ----------------
// Staging now issues global_load_lds via inline asm (s_mov m0 + global_load_lds_dwordx4)
// so the compiler has NO LDS-write dependency edge and cannot insert conservative
// s_waitcnt vmcnt(0) drains before each phase's ds_reads. All ordering is enforced
// by the hand-placed counted vmcnt waits + raw barriers ("memory"-clobbered).
// vmcnt FIFO (per-thread, 2 loads/unit): entering iter t: 4 in flight (B t+1).
// p1:+A_lo(t+1) p2:+A_hi(t+1) p3:+B1(t+2) p4:+B2(t+2) = 12; vmcnt(4) at end-p4
// retires the 8 oldest = ALL of tile t+1. WAR hazards barrier-separated (B(t+2)
// overwrites B(t) regions last read in p2, staged from p3; A(t+1) overwrites
// regions last read one full iteration earlier).
template <int KIND>
__device__ __forceinline__ void stage_unit(const ushort_t* __restrict__ G, int row0, int ld,
                                           int kc, ushort_t* s, int wave, int lane) {
  const int rsub = lane >> 3;
  const int cpos = lane & 7;
  typedef ushort_t __attribute__((address_space(3)))* as3p;
#pragma unroll
  for (int g = 0; g < 2; ++g) {
    const int idx = wave * 2 + g;
    int rg;
    if (KIND == 0)      rg = idx + (idx >= 8 ? 8 : 0);   // A rows 0-63,128-191
    else if (KIND == 1) rg = idx + 8 + (idx >= 8 ? 8 : 0); // A rows 64-127,192-255
    else if (KIND == 2) rg = idx;                          // B rows 0-127
    else                rg = idx + 16;                     // B rows 128-255
    const int r = rg * 8 + rsub;
    const int c = cpos ^ rsub;   // XOR-chunk pre-swizzle of the GLOBAL source
    const ushort_t* src = G + (size_t)(row0 + r) * (size_t)ld + (size_t)(kc + c * 8);
    const unsigned ldsoff =
        (unsigned)(uintptr_t)(as3p)(void*)(s + rg * 512);  // wave-uniform
    const unsigned ldsu = __builtin_amdgcn_readfirstlane(ldsoff);
    asm volatile("s_mov_b32 m0, %0\n\t"
                 "global_load_lds_dwordx4 %1, off"
                 :: "s"(ldsu), "v"(src)
                 : "memory");
  }
}

__device__ __forceinline__ short8 lds_frag(const ushort_t* s, int row, int chunk) {
  return *(const short8*)(s + row * 64 + ((chunk ^ (row & 7)) * 8));
}

__global__ __launch_bounds__(512, 2) void k_gemm256(
    const ushort_t* __restrict__ A, int lda,
    const ushort_t* __restrict__ Bt, int ldb,
    int nB, int Kdim, int mode,
    float* __restrict__ outF, ushort_t* __restrict__ outB, int ldc,
    const float* __restrict__ bias,
    const ushort_t* __restrict__ zmat, int ldz,
    const float* __restrict__ resid) {
  __shared__ alignas(16) ushort_t smem[65536];  // 128 KiB: buf0{A,B} | buf1{A,B}
  const int tid = threadIdx.x;
  const int wave = tid >> 6, lane = tid & 63;
  const int wm = wave >> 2, wn = wave & 3;
  const int quad = lane >> 4, l16 = lane & 15;

  const int per = gridDim.x >> 3;
  const int xcd = blockIdx.x & 7, slot = blockIdx.x >> 3;
  const int tile = xcd * per + slot;
  const int m0 = (tile / nB) * 256, n0 = (tile % nB) * 256;
  const int NT = Kdim >> 6;

  floatx4 acc[8][4];
#pragma unroll
  for (int i = 0; i < 8; ++i)
#pragma unroll
    for (int j = 0; j < 4; ++j) acc[i][j] = floatx4{0.f, 0.f, 0.f, 0.f};

  // prologue: tile0 {B1,B2,A_lo,A_hi} + tile1 {B1,B2}; wait tile0, leave 4 in flight
  stage_unit<2>(Bt, n0, ldb, 0, smem + 16384, wave, lane);
  stage_unit<3>(Bt, n0, ldb, 0, smem + 16384, wave, lane);
  stage_unit<0>(A, m0, lda, 0, smem, wave, lane);
  stage_unit<1>(A, m0, lda, 0, smem, wave, lane);
  if (NT > 1) {
    stage_unit<2>(Bt, n0, ldb, 64, smem + 32768 + 16384, wave, lane);
    stage_unit<3>(Bt, n0, ldb, 64, smem + 32768 + 16384, wave, lane);
    asm volatile("s_waitcnt vmcnt(4)" ::: "memory");
  } else {
    asm volatile("s_waitcnt vmcnt(0)" ::: "memory");
  }
  __builtin_amdgcn_s_barrier();

  short8 af[2][4], bf[2][2][2];
  const int rowA = wm * 128 + l16;
  const int rowB = wn * 64 + l16;

  for (int t = 0; t < NT; ++t) {
    ushort_t* sAc = smem + (t & 1) * 32768;
    ushort_t* sBc = sAc + 16384;
    ushort_t* sAn = smem + ((t + 1) & 1) * 32768;
    const int kc1 = (t + 1) << 6, kc2 = (t + 2) << 6;
    const bool pA = (t + 1 < NT), pB = (t + 2 < NT);

    // ---- phase 1: Q0 (m 0-3, n 0-1), stage A_lo(t+1) -> next buf
#pragma unroll
    for (int kk = 0; kk < 2; ++kk) {
#pragma unroll
      for (int i = 0; i < 4; ++i) af[kk][i] = lds_frag(sAc, rowA + i * 16, kk * 4 + quad);
#pragma unroll
      for (int j = 0; j < 2; ++j) bf[0][kk][j] = lds_frag(sBc, rowB + j * 16, kk * 4 + quad);
    }
    if (pA) stage_unit<0>(A, m0, lda, kc1, sAn, wave, lane);
    __builtin_amdgcn_s_barrier();
    asm volatile("s_waitcnt lgkmcnt(0)" ::: "memory");
    __builtin_amdgcn_s_setprio(1);
#pragma unroll
    for (int kk = 0; kk < 2; ++kk)
#pragma unroll
      for (int i = 0; i < 4; ++i)
#pragma unroll
        for (int j = 0; j < 2; ++j)
          acc[i][j] = __builtin_amdgcn_mfma_f32_16x16x32_bf16(af[kk][i], bf[0][kk][j], acc[i][j], 0, 0, 0);
    __builtin_amdgcn_s_setprio(0);
    __builtin_amdgcn_s_barrier();

    // ---- phase 2: Q1 (m 0-3, n 2-3), stage A_hi(t+1) -> next buf
#pragma unroll
    for (int kk = 0; kk < 2; ++kk)
#pragma unroll
      for (int j = 0; j < 2; ++j) bf[1][kk][j] = lds_frag(sBc, rowB + (2 + j) * 16, kk * 4 + quad);
    if (pA) stage_unit<1>(A, m0, lda, kc1, sAn, wave, lane);
    __builtin_amdgcn_s_barrier();
    asm volatile("s_waitcnt lgkmcnt(0)" ::: "memory");
    __builtin_amdgcn_s_setprio(1);
#pragma unroll
    for (int kk = 0; kk < 2; ++kk)
#pragma unroll
      for (int i = 0; i < 4; ++i)
#pragma unroll
        for (int j = 0; j < 2; ++j)
          acc[i][2 + j] = __builtin_amdgcn_mfma_f32_16x16x32_bf16(af[kk][i], bf[1][kk][j], acc[i][2 + j], 0, 0, 0);
    __builtin_amdgcn_s_setprio(0);
    __builtin_amdgcn_s_barrier();

    // ---- phase 3: Q2 (m 4-7, n 0-1), stage B1(t+2) -> CURRENT buf (B consumed @p2)
#pragma unroll
    for (int kk = 0; kk < 2; ++kk)
#pragma unroll
      for (int i = 0; i < 4; ++i) af[kk][i] = lds_frag(sAc, rowA + 64 + i * 16, kk * 4 + quad);
    if (pB) stage_unit<2>(Bt, n0, ldb, kc2, sBc, wave, lane);
    __builtin_amdgcn_s_barrier();
    asm volatile("s_waitcnt lgkmcnt(0)" ::: "memory");
    __builtin_amdgcn_s_setprio(1);
#pragma unroll
    for (int kk = 0; kk < 2; ++kk)
#pragma unroll
      for (int i = 0; i < 4; ++i)
#pragma unroll
        for (int j = 0; j < 2; ++j)
          acc[4 + i][j] = __builtin_amdgcn_mfma_f32_16x16x32_bf16(af[kk][i], bf[0][kk][j], acc[4 + i][j], 0, 0, 0);
    __builtin_amdgcn_s_setprio(0);
    __builtin_amdgcn_s_barrier();

    // ---- phase 4: Q3 (m 4-7, n 2-3), stage B2(t+2) -> CURRENT buf; tile-boundary vmcnt
    if (pB) stage_unit<3>(Bt, n0, ldb, kc2, sBc, wave, lane);
    __builtin_amdgcn_s_barrier();
    __builtin_amdgcn_s_setprio(1);
#pragma unroll
    for (int kk = 0; kk < 2; ++kk)
#pragma unroll
      for (int i = 0; i < 4; ++i)
#pragma unroll
        for (int j = 0; j < 2; ++j)
          acc[4 + i][2 + j] = __builtin_amdgcn_mfma_f32_16x16x32_bf16(af[kk][i], bf[1][kk][j], acc[4 + i][2 + j], 0, 0, 0);
    __builtin_amdgcn_s_setprio(0);
    if (pB) asm volatile("s_waitcnt vmcnt(4)" ::: "memory");  // tile t+1 landed; B(t+2) in flight
    else    asm volatile("s_waitcnt vmcnt(0)" ::: "memory");  // pipeline drain (last 2 tiles)
    __builtin_amdgcn_s_barrier();
  }

  // Epilogue through LDS: acc (col=lane&15, row=quad*4+reg) -> bf16 [256][256]
#pragma unroll
  for (int i = 0; i < 8; ++i)
#pragma unroll
    for (int j = 0; j < 4; ++j)
#pragma unroll
      for (int rg = 0; rg < 4; ++rg) {
        const int r = wm * 128 + i * 16 + quad * 4 + rg;
        const int c = wn * 64 + j * 16 + l16;
        smem[r * 256 + c] = f2bf(acc[i][j][rg]);
      }
  __syncthreads();

#pragma unroll
  for (int p = 0; p < 16; ++p) {
    const int r = p * 16 + (tid >> 5);
    const int c = (tid & 31) * 8;
    short8 v8 = *(const short8*)(smem + r * 256 + c);
    const size_t m = (size_t)(m0 + r);
    const int n = n0 + c;
    if (mode == 0) {
      *(short8*)(outB + m * (size_t)ldc + n) = v8;
    } else if (mode == 1) {
      float* o = outF + m * (size_t)ldc + n;
#pragma unroll
      for (int e = 0; e < 8; ++e) o[e] = bf2f((ushort_t)v8[e]);
    } else if (mode == 2) {
      const short8 z8 = *(const short8*)(zmat + m * (size_t)ldz + n);
      short8 o;
#pragma unroll
      for (int e = 0; e < 8; ++e) {
        const float v = bf2f((ushort_t)v8[e]) + bias[n + e];
        const float zf = bf2f((ushort_t)z8[e]);
        o[e] = (short)f2bf(v * (zf / (1.f + __expf(-zf))));
      }
      *(short8*)(outB + m * (size_t)ldc + n) = o;
    } else {
      const float* rs = resid + m * (size_t)ldc + n;
      float* o = outF + m * (size_t)ldc + n;
#pragma unroll
      for (int e = 0; e < 8; ++e) o[e] = bf2f((ushort_t)v8[e]) + rs[e];
    }
  }
}

// ---------------- host ----------------
extern "C" void kernel_launch(void* const* d_in, const int* in_sizes, int n_in,
                              void* d_out, int out_size, void* d_ws, size_t ws_size,
                              hipStream_t stream) {
  const float* x      = (const float*)d_in[0];
  const float* norm_w = (const float*)d_in[1];
  const float* W1     = (const float*)d_in[2];
  const float* W2     = (const float*)d_in[3];
  const float* Wlast  = (const float*)d_in[4];
  const float* conv_w = (const float*)d_in[5];
  const float* conv_b = (const float*)d_in[6];
  const float* Aarr   = (const float*)d_in[7];
  const float* Bw     = (const float*)d_in[8];
  const float* Bb     = (const float*)d_in[9];
  const float* Cw     = (const float*)d_in[10];
  const float* Cb     = (const float*)d_in[11];
  const float* Dw     = (const float*)d_in[12];
  const float* Db     = (const float*)d_in[13];
  const float* dwm    = (const float*)d_in[14];
  const float* dbv    = (const float*)d_in[15];

  char* ws = (char*)d_ws;
  ushort_t* xz   = (ushort_t*)(ws + 0);           // M x 2048 bf16 (x_b | z), 128 MB
  ushort_t* acat = (ushort_t*)(ws + 134217728);   // M x 1088 bf16 (xc | h), ~68 MB
  float*   preG  = (float*)(ws + 205520896);      // 128 x M f32 (transposed), 16 MB
  ushort_t* hT   = (ushort_t*)(ws + 222298112);   // 64 x M bf16, 4 MB
  ushort_t* xnu  = (ushort_t*)(ws + 226492416);   // M x 1024 bf16: xn, later u. 64 MB
  ushort_t* wcat = (ushort_t*)(ws + 293601280);   // 2048 x 1024 bf16 (W1; W2), 4 MB
  ushort_t* wlb  = (ushort_t*)(ws + 297795584);   // 1024 x 1024 bf16, 2 MB
  ushort_t* dwbw = (ushort_t*)(ws + 299892736);   // 128 x 1024 bf16 (dw; Bw), 256 KB
  ushort_t* bcat = (ushort_t*)(ws + 300154880);   // 1024 x 1088 bf16 (Dw | Cw), ~2.2 MB
  float*  biasCD = (float*)(ws + 302383104);      // 1024 f32
  float*   outF  = (float*)d_out;

  // 0. fused weight prep (one launch)
  {
    const int total = 3 * DD + 2 * HD + DDIM * KCAT + DDIM;
    k_prep<<<(total + 255) / 256, 256, 0, stream>>>(W1, W2, Wlast, dwm, Bw, Dw, Cw, Cb, Db,
                                                    wcat, wlb, dwbw, bcat, biasCD);
  }

  // 1. RMSNorm -> xn
  k_rms<<<MROWS, 256, 0, stream>>>(x, norm_w, xnu);

  // 2. [x_b | z] = xn @ [W1;W2].T  (fused, N=2048) — 256x256 8-phase, asm staging
  k_gemm256<<<(MROWS / 256) * 8, 512, 0, stream>>>(xnu, DDIM, wcat, DDIM, 8, DDIM, 0,
                                                   nullptr, xz, 2048, nullptr, nullptr, 0, nullptr);

  // 3. conv + silu -> acat cols [0,1024)
  k_conv<<<(MROWS * DDIM) / (256 * 8), 256, 0, stream>>>(xz, conv_w, conv_b, acat);

  // 4. preG_T = [dw;Bw] @ xc.T  (M=128 output — 128x128 kernel)
  k_gemm<<<256, 256, 0, stream>>>(dwbw, DDIM, acat, KCAT, 256, DDIM, 1,
                                  preG, nullptr, MROWS, nullptr, nullptr, 0, nullptr);

  // 5+6. fused delta + selective scan -> hT (transposed)
  k_scan<<<BDIM * HDIM, 256, 0, stream>>>(preG, dbv, Bb, Aarr, hT);

  // 6b. transpose hT into acat cols [1024,1088)
  k_htrans<<<MROWS / 256, 256, 0, stream>>>(hT, acat);

  // 7. u = (h@Cw.T + xc@Dw.T + Cb + Db) * silu(z)   (K=1088 concat GEMM, 128x128)
  k_gemm<<<256 * 8, 256, 0, stream>>>(acat, KCAT, bcat, KCAT, 8, KCAT, 2,
                                      nullptr, xnu, DDIM, biasCD, xz + DDIM, 2048, nullptr);

  // 8. out = u @ Wlast.T + x  (128x128)
  k_gemm<<<256 * 8, 256, 0, stream>>>(xnu, DDIM, wlb, DDIM, 8, DDIM, 3,
                                      outF, nullptr, DDIM, nullptr, nullptr, 0, x);

  (void)in_sizes; (void)n_in; (void)out_size; (void)ws_size;
}

// Round 3
// 658.323 us; speedup vs baseline: 1.0440x; 1.0286x over previous
//
#include <hip/hip_runtime.h>
#include <stdint.h>
#include <stddef.h>

#define TDIM 4096
#define DDIM 1024
#define HDIM 64
#define BDIM 8
#define MROWS (BDIM * TDIM)   // 32768
#define KCAT (DDIM + HDIM)    // 1088
#define DD (DDIM * DDIM)
#define HD (HDIM * DDIM)

typedef unsigned short ushort_t;
typedef __attribute__((ext_vector_type(8))) short short8;
typedef __attribute__((ext_vector_type(4))) float floatx4;

__device__ __forceinline__ unsigned short f2bf(float f) {
  unsigned u = __float_as_uint(f);
  u += 0x7fffu + ((u >> 16) & 1u);          // round-to-nearest-even
  return (unsigned short)(u >> 16);
}
__device__ __forceinline__ float bf2f(unsigned short s) {
  return __uint_as_float(((unsigned)s) << 16);
}
__device__ __forceinline__ float softplusf(float x) {
  return x > 20.f ? x : log1pf(expf(x));
}

// ---------------- fused weight prep (one launch) ----------------
__global__ void k_prep(const float* __restrict__ W1, const float* __restrict__ W2,
                       const float* __restrict__ Wlast, const float* __restrict__ dwm,
                       const float* __restrict__ Bw, const float* __restrict__ Dw,
                       const float* __restrict__ Cw, const float* __restrict__ Cb,
                       const float* __restrict__ Db,
                       ushort_t* __restrict__ wcat, ushort_t* __restrict__ wlb,
                       ushort_t* __restrict__ dwbw, ushort_t* __restrict__ bcat,
                       float* __restrict__ biasCD) {
  int i = blockIdx.x * 256 + threadIdx.x;
  if (i < DD) { wcat[i] = f2bf(W1[i]); return; }
  i -= DD;
  if (i < DD) { wcat[DD + i] = f2bf(W2[i]); return; }
  i -= DD;
  if (i < DD) { wlb[i] = f2bf(Wlast[i]); return; }
  i -= DD;
  if (i < HD) { dwbw[i] = f2bf(dwm[i]); return; }
  i -= HD;
  if (i < HD) { dwbw[HD + i] = f2bf(Bw[i]); return; }
  i -= HD;
  if (i < DDIM * KCAT) {
    const int row = i / KCAT, k = i - row * KCAT;
    const float v = (k < DDIM) ? Dw[row * DDIM + k] : Cw[row * HDIM + (k - DDIM)];
    bcat[i] = f2bf(v);
    return;
  }
  i -= DDIM * KCAT;
  if (i < DDIM) biasCD[i] = Cb[i] + Db[i];
}

// ---------------- RMSNorm: x (f32) -> xn (bf16) ----------------
__global__ __launch_bounds__(256) void k_rms(const float* __restrict__ x,
                                             const float* __restrict__ nw,
                                             ushort_t* __restrict__ xn) {
  const int row = blockIdx.x;
  const int tid = threadIdx.x;
  const size_t base = (size_t)row * DDIM + tid * 4;
  const float4 xv = *(const float4*)(x + base);
  float ss = xv.x * xv.x + xv.y * xv.y + xv.z * xv.z + xv.w * xv.w;
  for (int off = 32; off > 0; off >>= 1) ss += __shfl_down(ss, off, 64);
  __shared__ float sws[4];
  const int lane = tid & 63, w = tid >> 6;
  if (lane == 0) sws[w] = ss;
  __syncthreads();
  const float tot = sws[0] + sws[1] + sws[2] + sws[3];
  const float scale = rsqrtf(tot * (1.0f / DDIM) + 1.1920929e-7f);
  const float4 nwv = *(const float4*)(nw + tid * 4);
  ushort4 o;
  o.x = f2bf(xv.x * scale * nwv.x);
  o.y = f2bf(xv.y * scale * nwv.y);
  o.z = f2bf(xv.z * scale * nwv.z);
  o.w = f2bf(xv.w * scale * nwv.w);
  *(ushort4*)(xn + base) = o;
}

// ---------------- causal depthwise conv k=3 + silu (vectorized x8) ----------------
__global__ __launch_bounds__(256) void k_conv(const ushort_t* __restrict__ xz,
                                              const float* __restrict__ cw,
                                              const float* __restrict__ cb,
                                              ushort_t* __restrict__ acat) {
  const size_t eidx = ((size_t)blockIdx.x * 256 + threadIdx.x) * 8;  // over MROWS*DDIM
  const int d = (int)(eidx & (DDIM - 1));
  const size_t m = eidx >> 10;
  const int t = (int)(m & (TDIM - 1));
  const size_t s = m * 2048 + d;
  const short8 r2 = *(const short8*)(xz + s);
  short8 r1 = {0,0,0,0,0,0,0,0}, r0 = {0,0,0,0,0,0,0,0};
  if (t >= 1) r1 = *(const short8*)(xz + s - 2048);
  if (t >= 2) r0 = *(const short8*)(xz + s - 4096);
  short8 o;
#pragma unroll
  for (int e = 0; e < 8; ++e) {
    const int de = d + e;
    float v = bf2f((ushort_t)r2[e]) * cw[de * 3 + 2]
            + bf2f((ushort_t)r1[e]) * cw[de * 3 + 1]
            + bf2f((ushort_t)r0[e]) * cw[de * 3 + 0]
            + cb[de];
    o[e] = (short)f2bf(v / (1.f + __expf(-v)));
  }
  *(short8*)(acat + m * KCAT + d) = o;
}

// ---------------- fused delta + selective scan: one block per (b,h) channel ----------------
__global__ __launch_bounds__(256) void k_scan(const float* __restrict__ preG,
                                              const float* __restrict__ db,
                                              const float* __restrict__ Bb,
                                              const float* __restrict__ A,
                                              ushort_t* __restrict__ hT) {
  const int ch = blockIdx.x;           // 0..511
  const int b = ch >> 6, h = ch & 63;
  const int tid = threadIdx.x;
  const float dbh = db[h], Bbh = Bb[h];
  const float al = -softplusf(A[h]);
  const size_t base1 = (size_t)h * MROWS + (size_t)b * TDIM + (size_t)tid * 16;
  const size_t base2 = base1 + (size_t)64 * MROWS;

  float a[16], bbv[16];
#pragma unroll
  for (int k4 = 0; k4 < 4; ++k4) {
    const float4 p1 = *(const float4*)(preG + base1 + k4 * 4);
    const float4 p2 = *(const float4*)(preG + base2 + k4 * 4);
    const float pp1[4] = {p1.x, p1.y, p1.z, p1.w};
    const float pp2[4] = {p2.x, p2.y, p2.z, p2.w};
#pragma unroll
    for (int e = 0; e < 4; ++e) {
      const float delta = softplusf(pp1[e] + dbh);
      a[k4 * 4 + e] = delta * al;
      bbv[k4 * 4 + e] = delta * (pp2[e] + Bbh);
    }
  }
  float run = 0.f;
#pragma unroll
  for (int k = 0; k < 16; ++k) { run += a[k]; a[k] = run; }  // local inclusive

  __shared__ float sh[256];
  sh[tid] = run;
  __syncthreads();
  for (int s = 1; s < 256; s <<= 1) {
    float v = (tid >= s) ? sh[tid - s] : 0.f;
    __syncthreads();
    sh[tid] += v;
    __syncthreads();
  }
  const float off = (tid > 0) ? sh[tid - 1] : 0.f;
  __syncthreads();

  float term[16];
  float prev = off;  // exclusive prefix (unclipped)
#pragma unroll
  for (int k = 0; k < 16; ++k) {
    const float Pk = off + a[k];
    const float Ashift = fminf(fmaxf(prev, -20.f), 20.f);
    term[k] = bbv[k] * expf(-Ashift);
    a[k] = fminf(fmaxf(Pk, -20.f), 20.f);  // clipped A_cum
    prev = Pk;
  }

  float run2 = 0.f;
#pragma unroll
  for (int k = 0; k < 16; ++k) { run2 += term[k]; term[k] = run2; }
  sh[tid] = run2;
  __syncthreads();
  for (int s = 1; s < 256; s <<= 1) {
    float v = (tid >= s) ? sh[tid - s] : 0.f;
    __syncthreads();
    sh[tid] += v;
    __syncthreads();
  }
  const float off2 = (tid > 0) ? sh[tid - 1] : 0.f;

  ushort_t* dst = hT + (size_t)h * MROWS + (size_t)b * TDIM + (size_t)tid * 16;
#pragma unroll
  for (int k = 0; k < 16; ++k) {
    dst[k] = f2bf(expf(a[k]) * (off2 + term[k]));
  }
}

// ---------------- transpose hT[64][M] -> acat[:, 1024:1088] ----------------
__global__ __launch_bounds__(256) void k_htrans(const ushort_t* __restrict__ hT,
                                                ushort_t* __restrict__ acat) {
  __shared__ ushort_t t[64 * 256];
  const int tid = threadIdx.x;
  const int m0 = blockIdx.x * 256;
#pragma unroll
  for (int p = 0; p < 8; ++p) {
    const int e = p * 2048 + tid * 8;
    const int h = e >> 8, mm = e & 255;
    *(short8*)(t + e) = *(const short8*)(hT + (size_t)h * MROWS + m0 + mm);
  }
  __syncthreads();
  ushort_t* dst = acat + (size_t)(m0 + tid) * KCAT + DDIM;
#pragma unroll
  for (int p = 0; p < 8; ++p) {
    short8 v;
#pragma unroll
    for (int e = 0; e < 8; ++e) v[e] = t[(p * 8 + e) * 256 + tid];
    *(short8*)(dst + p * 8) = v;
  }
}

// ---------------- 128x128 GEMM: C[m,n] = sum_k A[m,k] * Bt[n,k], bf16 MFMA ----------------
// Proven 2-phase structure (round-0, 988 TF on step 2). MODE is now a template
// parameter so each pipeline step gets a DISTINCT kernel name in rocprof
// (k_gemm<0>=step2, <1>=step4, <2>=step7, <3>=step8) and the epilogue branch
// is compile-time.
__device__ __forceinline__ void stage128x64(const ushort_t* __restrict__ G, int row0,
                                            int ld, int kc, ushort_t* s, int wave, int lane) {
  const int rsub = lane >> 3;   // row within 8-row group
  const int cpos = lane & 7;    // dest chunk position
  using gp_t = const unsigned int __attribute__((address_space(1)))*;
  using lp_t = unsigned int __attribute__((address_space(3)))*;
#pragma unroll
  for (int g = 0; g < 4; ++g) {
    const int rg = wave * 4 + g;           // 0..15 row-group
    const int r = rg * 8 + rsub;           // tile row
    const int c = cpos ^ rsub;             // source chunk (r&7 == rsub)
    const ushort_t* src = G + (size_t)(row0 + r) * (size_t)ld + (size_t)(kc + c * 8);
    __builtin_amdgcn_global_load_lds((gp_t)(const void*)src, (lp_t)(void*)(s + rg * 512),
                                     16, 0, 0);
  }
}

template <int MODE>
__global__ __launch_bounds__(256, 4) void k_gemm(
    const ushort_t* __restrict__ A, int lda,
    const ushort_t* __restrict__ Bt, int ldb,
    int nB, int Kdim,
    float* __restrict__ outF, ushort_t* __restrict__ outB, int ldc,
    const float* __restrict__ bias,
    const ushort_t* __restrict__ zmat, int ldz,
    const float* __restrict__ resid) {
  __shared__ alignas(16) ushort_t smem[128 * 128];  // 32KB: sA | sB, reused as C-tile
  ushort_t* sA = smem;
  ushort_t* sB = smem + 128 * 64;
  const int tid = threadIdx.x;
  const int wave = tid >> 6, lane = tid & 63;

  // XCD swizzle: consecutive slots on one XCD walk n fastest -> A-strip reuse in L2
  const int per = gridDim.x >> 3;
  const int xcd = blockIdx.x & 7, slot = blockIdx.x >> 3;
  const int tile = xcd * per + slot;
  const int m0 = (tile / nB) * 128, n0 = (tile % nB) * 128;

  const int half_m = (wave & 1) * 64, half_n = (wave >> 1) * 64;
  const int quad = lane >> 4, l16 = lane & 15;

  floatx4 acc[4][4];
#pragma unroll
  for (int i = 0; i < 4; ++i)
#pragma unroll
    for (int j = 0; j < 4; ++j) acc[i][j] = floatx4{0.f, 0.f, 0.f, 0.f};

  for (int kc = 0; kc < Kdim; kc += 64) {
    stage128x64(A, m0, lda, kc, sA, wave, lane);
    stage128x64(Bt, n0, ldb, kc, sB, wave, lane);
    __syncthreads();
#pragma unroll
    for (int s = 0; s < 2; ++s) {
      short8 af[4], bfr[4];
#pragma unroll
      for (int i = 0; i < 4; ++i) {
        const int r = half_m + i * 16 + l16;
        const int cp = (s * 4 + quad) ^ (r & 7);
        af[i] = *(const short8*)(sA + r * 64 + cp * 8);
      }
#pragma unroll
      for (int j = 0; j < 4; ++j) {
        const int r = half_n + j * 16 + l16;
        const int cp = (s * 4 + quad) ^ (r & 7);
        bfr[j] = *(const short8*)(sB + r * 64 + cp * 8);
      }
#pragma unroll
      for (int i = 0; i < 4; ++i)
#pragma unroll
        for (int j = 0; j < 4; ++j)
          acc[i][j] = __builtin_amdgcn_mfma_f32_16x16x32_bf16(af[i], bfr[j], acc[i][j], 0, 0, 0);
    }
    __syncthreads();
  }

  // Epilogue through LDS: acc (C/D layout col=lane&15, row=quad*4+reg) -> bf16 tile
#pragma unroll
  for (int i = 0; i < 4; ++i)
#pragma unroll
    for (int j = 0; j < 4; ++j)
#pragma unroll
      for (int rg = 0; rg < 4; ++rg) {
        const int r = half_m + i * 16 + quad * 4 + rg;
        const int c = half_n + j * 16 + l16;
        smem[r * 128 + c] = f2bf(acc[i][j][rg]);
      }
  __syncthreads();

#pragma unroll
  for (int p = 0; p < 8; ++p) {
    const int r = p * 16 + (tid >> 4);
    const int c = (tid & 15) * 8;
    short8 v8 = *(const short8*)(smem + r * 128 + c);
    const size_t m = (size_t)(m0 + r);
    const int n = n0 + c;
    if (MODE == 0) {
      *(short8*)(outB + m * (size_t)ldc + n) = v8;
    } else if (MODE == 1) {
      float* o = outF + m * (size_t)ldc + n;
#pragma unroll
      for (int e = 0; e < 8; ++e) o[e] = bf2f((ushort_t)v8[e]);
    } else if (MODE == 2) {
      const short8 z8 = *(const short8*)(zmat + m * (size_t)ldz + n);
      short8 o;
#pragma unroll
      for (int e = 0; e < 8; ++e) {
        const float v = bf2f((ushort_t)v8[e]) + bias[n + e];
        const float zf = bf2f((ushort_t)z8[e]);
        o[e] = (short)f2bf(v * (zf / (1.f + __expf(-zf))));
      }
      *(short8*)(outB + m * (size_t)ldc + n) = o;
    } else {
      const float* rs = resid + m * (size_t)ldc + n;
      float* o = outF + m * (size_t)ldc + n;
#pragma unroll
      for (int e = 0; e < 8; ++e) o[e] = bf2f((ushort_t)v8[e]) + rs[e];
    }
  }
}

// ---------------- host ----------------
extern "C" void kernel_launch(void* const* d_in, const int* in_sizes, int n_in,
                              void* d_out, int out_size, void* d_ws, size_t ws_size,
                              hipStream_t stream) {
  const float* x      = (const float*)d_in[0];
  const float* norm_w = (const float*)d_in[1];
  const float* W1     = (const float*)d_in[2];
  const float* W2     = (const float*)d_in[3];
  const float* Wlast  = (const float*)d_in[4];
  const float* conv_w = (const float*)d_in[5];
  const float* conv_b = (const float*)d_in[6];
  const float* Aarr   = (const float*)d_in[7];
  const float* Bw     = (const float*)d_in[8];
  const float* Bb     = (const float*)d_in[9];
  const float* Cw     = (const float*)d_in[10];
  const float* Cb     = (const float*)d_in[11];
  const float* Dw     = (const float*)d_in[12];
  const float* Db     = (const float*)d_in[13];
  const float* dwm    = (const float*)d_in[14];
  const float* dbv    = (const float*)d_in[15];

  char* ws = (char*)d_ws;
  // workspace plan (bytes):
  ushort_t* xz   = (ushort_t*)(ws + 0);           // M x 2048 bf16 (x_b | z), 128 MB
  ushort_t* acat = (ushort_t*)(ws + 134217728);   // M x 1088 bf16 (xc | h), ~68 MB
  float*   preG  = (float*)(ws + 205520896);      // 128 x M f32 (transposed), 16 MB
  ushort_t* hT   = (ushort_t*)(ws + 222298112);   // 64 x M bf16, 4 MB
  ushort_t* xnu  = (ushort_t*)(ws + 226492416);   // M x 1024 bf16: xn, later u. 64 MB
  ushort_t* wcat = (ushort_t*)(ws + 293601280);   // 2048 x 1024 bf16 (W1; W2), 4 MB
  ushort_t* wlb  = (ushort_t*)(ws + 297795584);   // 1024 x 1024 bf16, 2 MB
  ushort_t* dwbw = (ushort_t*)(ws + 299892736);   // 128 x 1024 bf16 (dw; Bw), 256 KB
  ushort_t* bcat = (ushort_t*)(ws + 300154880);   // 1024 x 1088 bf16 (Dw | Cw), ~2.2 MB
  float*  biasCD = (float*)(ws + 302383104);      // 1024 f32
  float*   outF  = (float*)d_out;

  // 0. fused weight prep (one launch)
  {
    const int total = 3 * DD + 2 * HD + DDIM * KCAT + DDIM;
    k_prep<<<(total + 255) / 256, 256, 0, stream>>>(W1, W2, Wlast, dwm, Bw, Dw, Cw, Cb, Db,
                                                    wcat, wlb, dwbw, bcat, biasCD);
  }

  // 1. RMSNorm -> xn
  k_rms<<<MROWS, 256, 0, stream>>>(x, norm_w, xnu);

  // 2. [x_b | z] = xn @ [W1;W2].T  (fused, N=2048)
  k_gemm<0><<<256 * 16, 256, 0, stream>>>(xnu, DDIM, wcat, DDIM, 16, DDIM,
                                          nullptr, xz, 2048, nullptr, nullptr, 0, nullptr);

  // 3. conv + silu -> acat cols [0,1024)
  k_conv<<<(MROWS * DDIM) / (256 * 8), 256, 0, stream>>>(xz, conv_w, conv_b, acat);

  // 4. preG_T = [dw;Bw] @ xc.T  (operand-swapped: output 128 x M row-major, coalesced)
  k_gemm<1><<<256, 256, 0, stream>>>(dwbw, DDIM, acat, KCAT, 256, DDIM,
                                     preG, nullptr, MROWS, nullptr, nullptr, 0, nullptr);

  // 5+6. fused delta + selective scan -> hT (transposed)
  k_scan<<<BDIM * HDIM, 256, 0, stream>>>(preG, dbv, Bb, Aarr, hT);

  // 6b. transpose hT into acat cols [1024,1088)
  k_htrans<<<MROWS / 256, 256, 0, stream>>>(hT, acat);

  // 7. u = (h@Cw.T + xc@Dw.T + Cb + Db) * silu(z)   (K=1088 concat GEMM)
  k_gemm<2><<<256 * 8, 256, 0, stream>>>(acat, KCAT, bcat, KCAT, 8, KCAT,
                                         nullptr, xnu, DDIM, biasCD, xz + DDIM, 2048, nullptr);

  // 8. out = u @ Wlast.T + x
  k_gemm<3><<<256 * 8, 256, 0, stream>>>(xnu, DDIM, wlb, DDIM, 8, DDIM,
                                         outF, nullptr, DDIM, nullptr, nullptr, 0, x);

  (void)in_sizes; (void)n_in; (void)out_size; (void)ws_size;
}